// Round 14
// baseline (193.644 us; speedup 1.0000x reference)
//
#include <hip/hip_runtime.h>

typedef __bf16 bf16;
typedef __attribute__((ext_vector_type(8))) bf16 bf16x8;
typedef __attribute__((ext_vector_type(4))) float f32x4;

// async global->LDS (LDS dest is wave-uniform base + lane*16)
#define GLDS16(g, l) __builtin_amdgcn_global_load_lds( \
    (const __attribute__((address_space(1))) void*)(g), \
    (__attribute__((address_space(3))) void*)(l), 16, 0, 0)

// log2(e)/sqrt(128): folded into q at the QKV epilogue so softmax uses exp2 directly
#define QSCALE 0.12751744f

static __device__ __forceinline__ f32x4 MFMA(bf16x8 a, bf16x8 b, f32x4 c) {
    return __builtin_amdgcn_mfma_f32_16x16x32_bf16(a, b, c, 0, 0, 0);
}

// ---------------------------------------------------------------- convert f32->bf16
__global__ __launch_bounds__(256) void convert_kernel(
    const float* __restrict__ x, const float* __restrict__ wq,
    const float* __restrict__ wk, const float* __restrict__ wv,
    const float* __restrict__ wp,
    bf16* __restrict__ xb, bf16* __restrict__ wqkvb, bf16* __restrict__ wpb)
{
    int bid = blockIdx.x;
    const float* src; bf16* dst; int base;
    if (bid < 4096)      { src = x;  dst = xb;              base = bid * 2048; }
    else if (bid < 4608) { src = wq; dst = wqkvb;           base = (bid - 4096) * 2048; }
    else if (bid < 5120) { src = wk; dst = wqkvb + 1048576; base = (bid - 4608) * 2048; }
    else if (bid < 5632) { src = wv; dst = wqkvb + 2097152; base = (bid - 5120) * 2048; }
    else                 { src = wp; dst = wpb;             base = (bid - 5632) * 2048; }
    int i = base + threadIdx.x * 8;
    const f32x4* s4 = (const f32x4*)(src + i);
    f32x4 a = s4[0], c = s4[1];
    bf16x8 v;
    #pragma unroll
    for (int e = 0; e < 4; ++e) { v[e] = (bf16)a[e]; v[e + 4] = (bf16)c[e]; }
    *(bf16x8*)(dst + i) = v;
}

// ---------------------------------------------------------------- 128^2 BK=64 GEMM
// v8 = R7/R10 kernel (measured best, 92 us QKV) with ONE change: L2-aware XCD
// tiling. Old mapping gave each XCD all 24 n-tiles -> per-XCD B working set
// 6 MB > 4 MB XCD-L2 -> B thrashed L2; staging ran at the ~8 TB/s L3 path
// (FETCH 110 MB). New mapping: XCD x owns n-tiles [x*NPX, (x+1)*NPX) x all
// m-tiles, mi-major-inner (the NPX nl-siblings of an mi run back-to-back):
// per-XCD L2 working set = NPX B-tiles (0.75 MB) hot + streaming A.
// B staged from L2; A read ~once per XCD from L3. Bijective (NTN % 8 == 0 or
// NPX == 1 exact). Everything else byte-identical to R10.
template <int MODE, int NTN>
__global__ __launch_bounds__(256, 2) void gemm2(
    const bf16* __restrict__ A, const bf16* __restrict__ B,
    const float* __restrict__ bias0, const float* __restrict__ bias1,
    const float* __restrict__ bias2,
    bf16* __restrict__ q_out, bf16* __restrict__ k_out, bf16* __restrict__ vt_out,
    float* __restrict__ f_out)
{
    constexpr int K = 1024;
    constexpr int NT = K / 64;        // 16 K-tiles
    constexpr int NPX = NTN / 8;      // n-tiles per XCD (3 for QKV, 1 for proj)
    const int tid = threadIdx.x;
    const int lane = tid & 63;
    const int wid = tid >> 6;
    const int wr = wid >> 1, wc = wid & 1;
    const int l15 = lane & 15, l4 = lane >> 4, l7 = lane & 7;

    // L2-aware XCD tiling (blocks round-robin XCDs by blockIdx & 7)
    const int xcd = blockIdx.x & 7;
    const int seq = blockIdx.x >> 3;          // [0, NWG/8)
    const int mi = seq / NPX;
    const int nl = seq % NPX;
    const int m0 = mi * 128;
    const int n0 = (xcd * NPX + nl) * 128;

    __shared__ __align__(16) bf16 lds[2][2][8192];  // [buf][A,B][128 x 64]

    const int rr = tid >> 3, pc = tid & 7;
    auto stage = [&](int buf, int t) {
        #pragma unroll
        for (int c = 0; c < 4; ++c) {
            int row = c * 32 + rr;
            int lc = pc ^ (row & 7);
            GLDS16(A + (size_t)(m0 + row) * K + t * 64 + lc * 8,
                   &lds[buf][0][c * 2048 + tid * 8]);
        }
        #pragma unroll
        for (int c = 0; c < 4; ++c) {
            int row = c * 32 + rr;
            int lc = pc ^ (row & 7);
            GLDS16(B + (size_t)(n0 + row) * K + t * 64 + lc * 8,
                   &lds[buf][1][c * 2048 + tid * 8]);
        }
    };

    const int arow = wr * 64 + l15;
    const int brow = wc * 64 + l15;
    #define RA(buf, f, kk) (*(const bf16x8*)((const char*)lds[buf][0] + \
        (arow + (f) * 16) * 128 + ((((kk) * 4 + l4) ^ l7) * 16)))
    #define RB(buf, j, kk) (*(const bf16x8*)((const char*)lds[buf][1] + \
        (brow + (j) * 16) * 128 + ((((kk) * 4 + l4) ^ l7) * 16)))

    f32x4 acc[4][4];
    #pragma unroll
    for (int f = 0; f < 4; ++f)
        #pragma unroll
        for (int j = 0; j < 4; ++j)
            #pragma unroll
            for (int e = 0; e < 4; ++e) acc[f][j][e] = 0.f;

    stage(0, 0);
    __syncthreads();

    for (int t = 0; t < NT; ++t) {
        const int buf = t & 1;
        if (t + 1 < NT) stage(buf ^ 1, t + 1);   // issue next-tile loads FIRST
        bf16x8 af[4][2], bfr[4][2];
        #pragma unroll
        for (int f = 0; f < 4; ++f) { af[f][0] = RA(buf, f, 0); af[f][1] = RA(buf, f, 1); }
        #pragma unroll
        for (int j = 0; j < 4; ++j) { bfr[j][0] = RB(buf, j, 0); bfr[j][1] = RB(buf, j, 1); }
        __builtin_amdgcn_s_setprio(1);
        #pragma unroll
        for (int f = 0; f < 4; ++f)
            #pragma unroll
            for (int j = 0; j < 4; ++j) {
                acc[f][j] = MFMA(af[f][0], bfr[j][0], acc[f][j]);
                acc[f][j] = MFMA(af[f][1], bfr[j][1], acc[f][j]);
            }
        __builtin_amdgcn_s_setprio(0);
        __syncthreads();   // drains vmcnt (stage had the whole phase to land)
    }
    #undef RA
    #undef RB

    // epilogue: C/D layout col = lane&15, row = (lane>>4)*4 + reg  [m89-verified]
    #pragma unroll
    for (int f = 0; f < 4; ++f) {
        #pragma unroll
        for (int j = 0; j < 4; ++j) {
            #pragma unroll
            for (int r = 0; r < 4; ++r) {
                int m = m0 + wr * 64 + f * 16 + l4 * 4 + r;
                int n = n0 + wc * 64 + j * 16 + l15;
                float v = acc[f][j][r];
                if (MODE == 0) {
                    if (n0 < 1024) {
                        q_out[m * 1024 + n] = (bf16)((v + bias0[n]) * QSCALE);
                    } else if (n0 < 2048) {
                        int nn = n - 1024;
                        k_out[m * 1024 + nn] = (bf16)(v + bias1[nn]);
                    } else {
                        int nn = n - 2048;
                        int hl = nn >> 7, d = nn & 127;
                        int bb = m >> 10, tt = m & 1023;
                        vt_out[((bb * 8 + hl) * 128 + d) * 1024 + tt] = (bf16)(v + bias2[nn]);
                    }
                } else {
                    f_out[m * 1024 + n] = v + bias0[n];
                }
            }
        }
    }
}

// ---------------------------------------------------------------- flash attention v4
// grid: 512 = B(8)*H(8)*(T/128); 4 waves/block, each wave owns 32 q-rows.
// QBLK=128 (bytes/MFMA 0.56 KB), un-subtracted softmax, dbuf single-barrier,
// setprio. LDS 80 KiB -> 2 blocks/CU. (unchanged from R10 -- measured good)
__global__ __launch_bounds__(256, 2) void attn_kernel(
    const bf16* __restrict__ qb, const bf16* __restrict__ kb,
    const bf16* __restrict__ vtb, const int* __restrict__ mask,
    bf16* __restrict__ yb)
{
    const int tid = threadIdx.x;
    const int lane = tid & 63;
    const int wid = tid >> 6;
    const int g = blockIdx.x;
    const int orig = (g & 7) * 64 + (g >> 3);   // bijective XCD swizzle (512 = 8*64)
    const int bh = orig >> 3;
    const int qt = orig & 7;
    const int b = bh >> 3;
    const int h = bh & 7;
    const int m0 = b * 1024 + qt * 128;
    const int l15 = lane & 15, l4 = lane >> 4;

    __shared__ __align__(16) char smem[81920];
    auto stageKV = [&](int bufKV, int kt) {
        char* Kb = smem + bufKV * 16384;
        char* Vb = smem + 32768 + bufKV * 16384;
        #pragma unroll
        for (int n = 0; n < 4; ++n)
            GLDS16(kb + (b * 1024 + kt + n * 16 + (tid >> 4)) * 1024 + h * 128 +
                       (((tid & 15) ^ ((tid >> 4) & 7)) * 8),
                   Kb + n * 4096 + tid * 16);
        #pragma unroll
        for (int n = 0; n < 4; ++n)
            GLDS16(vtb + (bh * 128 + n * 32 + (tid >> 3)) * 1024 + kt +
                       (((tid & 7) ^ ((tid >> 3) & 7)) * 8),
                   Vb + n * 4096 + tid * 16);
    };

    bf16x8 qf[2][4];
    #pragma unroll
    for (int i = 0; i < 2; ++i)
        #pragma unroll
        for (int kc = 0; kc < 4; ++kc)
            qf[i][kc] = *(const bf16x8*)(qb +
                (m0 + wid * 32 + i * 16 + l15) * 1024 + h * 128 + kc * 32 + l4 * 8);

    f32x4 o[2][8];
    #pragma unroll
    for (int i = 0; i < 2; ++i)
        #pragma unroll
        for (int jd = 0; jd < 8; ++jd)
            #pragma unroll
            for (int e = 0; e < 4; ++e) o[i][jd][e] = 0.f;
    float l_run[2][4];
    #pragma unroll
    for (int i = 0; i < 2; ++i)
        #pragma unroll
        for (int r = 0; r < 4; ++r) l_run[i][r] = 0.f;

    stageKV(0, 0);
    __syncthreads();

    for (int t = 0; t < 16; ++t) {
        const int buf = t & 1;
        const int kt = t * 64;
        if (t + 1 < 16) stageKV(buf ^ 1, kt + 64);   // issue next K/V FIRST

        int mv[4];
        #pragma unroll
        for (int j = 0; j < 4; ++j)
            mv[j] = mask[b * 1024 + kt + j * 16 + l15];

        const char* Ks = smem + buf * 16384;
        const char* Vs = smem + 32768 + buf * 16384;

        f32x4 s[2][4];
        #pragma unroll
        for (int i = 0; i < 2; ++i)
            #pragma unroll
            for (int j = 0; j < 4; ++j)
                #pragma unroll
                for (int e = 0; e < 4; ++e) s[i][j][e] = 0.f;
        #pragma unroll
        for (int kc = 0; kc < 4; ++kc) {
            bf16x8 kf[4];
            #pragma unroll
            for (int j = 0; j < 4; ++j)
                kf[j] = *(const bf16x8*)(Ks + (j * 16 + l15) * 256 +
                    (((kc * 4 + l4) ^ (lane & 7)) * 16));
            __builtin_amdgcn_s_setprio(1);
            #pragma unroll
            for (int i = 0; i < 2; ++i)
                #pragma unroll
                for (int j = 0; j < 4; ++j)
                    s[i][j] = MFMA(qf[i][kc], kf[j], s[i][j]);
            __builtin_amdgcn_s_setprio(0);
        }

        #pragma unroll
        for (int i = 0; i < 2; ++i)
            #pragma unroll
            for (int j = 0; j < 4; ++j) {
                if (mv[j] == 0) {
                    #pragma unroll
                    for (int e = 0; e < 4; ++e) s[i][j][e] = -1e30f;
                }
                #pragma unroll
                for (int r = 0; r < 4; ++r) {
                    float p = __builtin_amdgcn_exp2f(s[i][j][r]);
                    s[i][j][r] = p;
                    l_run[i][r] += p;
                }
            }

        #pragma unroll
        for (int i = 0; i < 2; ++i)
            #pragma unroll
            for (int j = 0; j < 4; ++j)
                #pragma unroll
                for (int r = 0; r < 4; ++r) {
                    int row = i * 16 + l4 * 4 + r;
                    int col = j * 16 + l15;
                    *(bf16*)(smem + 65536 + wid * 4096 + row * 128 +
                             (((col >> 3) ^ (row & 7)) * 16) + (col & 7) * 2) =
                        (bf16)s[i][j][r];
                }

        #pragma unroll
        for (int k2 = 0; k2 < 2; ++k2) {
            bf16x8 pa[2];
            #pragma unroll
            for (int i = 0; i < 2; ++i)
                pa[i] = *(const bf16x8*)(smem + 65536 + wid * 4096 +
                    (i * 16 + l15) * 128 + (((k2 * 4 + l4) ^ (l15 & 7)) * 16));
            __builtin_amdgcn_s_setprio(1);
            #pragma unroll
            for (int jd = 0; jd < 8; ++jd) {
                bf16x8 vf = *(const bf16x8*)(Vs + (jd * 16 + l15) * 128 +
                    (((k2 * 4 + l4) ^ (l15 & 7)) * 16));
                o[0][jd] = MFMA(pa[0], vf, o[0][jd]);
                o[1][jd] = MFMA(pa[1], vf, o[1][jd]);
            }
            __builtin_amdgcn_s_setprio(0);
        }
        __syncthreads();
    }

    #pragma unroll
    for (int off = 8; off >= 1; off >>= 1)
        #pragma unroll
        for (int i = 0; i < 2; ++i)
            #pragma unroll
            for (int r = 0; r < 4; ++r) l_run[i][r] += __shfl_xor(l_run[i][r], off);
    #pragma unroll
    for (int i = 0; i < 2; ++i) {
        float inv[4];
        #pragma unroll
        for (int r = 0; r < 4; ++r) inv[r] = 1.0f / fmaxf(l_run[i][r], 1e-30f);
        #pragma unroll
        for (int jd = 0; jd < 8; ++jd)
            #pragma unroll
            for (int r = 0; r < 4; ++r)
                yb[(m0 + wid * 32 + i * 16 + l4 * 4 + r) * 1024 +
                   h * 128 + jd * 16 + l15] = (bf16)(o[i][jd][r] * inv[r]);
    }
}

// ---------------------------------------------------------------- launch
extern "C" void kernel_launch(void* const* d_in, const int* in_sizes, int n_in,
                              void* d_out, int out_size, void* d_ws, size_t ws_size,
                              hipStream_t stream)
{
    (void)in_sizes; (void)n_in; (void)out_size; (void)ws_size;
    const float* x  = (const float*)d_in[0];
    const int* mask = (const int*)d_in[1];
    const float* Wq = (const float*)d_in[2];
    const float* bq = (const float*)d_in[3];
    const float* Wk = (const float*)d_in[4];
    const float* bk = (const float*)d_in[5];
    const float* Wv = (const float*)d_in[6];
    const float* bv = (const float*)d_in[7];
    const float* Wp = (const float*)d_in[8];
    const float* bp = (const float*)d_in[9];
    float* out = (float*)d_out;

    char* ws = (char*)d_ws;
    bf16* xb    = (bf16*)(ws);                      // 16 MB  x bf16 (8192 x 1024)
    bf16* wqkvb = (bf16*)(ws + (16u << 20));        //  6 MB  [Wq;Wk;Wv]
    bf16* wpb   = (bf16*)(ws + (22u << 20));        //  2 MB  Wp
    bf16* qbuf  = (bf16*)(ws + (24u << 20));        // 16 MB  q (scaled)
    bf16* kbuf  = (bf16*)(ws + (40u << 20));        // 16 MB  k
    bf16* vtb   = (bf16*)(ws + (56u << 20));        // 16 MB  v^T per (b,h)
    bf16* ybuf  = (bf16*)(ws + (72u << 20));        // 16 MB  attention out

    convert_kernel<<<6144, 256, 0, stream>>>(x, Wq, Wk, Wv, Wp, xb, wqkvb, wpb);
    gemm2<0, 24><<<1536, 256, 0, stream>>>(xb, wqkvb, bq, bk, bv,
                                           qbuf, kbuf, vtb, nullptr);
    attn_kernel<<<512, 256, 0, stream>>>(qbuf, kbuf, vtb, mask, ybuf);
    gemm2<1, 8><<<512, 256, 0, stream>>>(ybuf, wpb, bp, nullptr, nullptr,
                                         nullptr, nullptr, nullptr, out);
}

// Round 15
// 176.690 us; speedup vs baseline: 1.0960x; 1.0960x over previous
//
#include <hip/hip_runtime.h>

typedef __bf16 bf16;
typedef __attribute__((ext_vector_type(8))) bf16 bf16x8;
typedef __attribute__((ext_vector_type(4))) float f32x4;

// async global->LDS (LDS dest is wave-uniform base + lane*16)
#define GLDS16(g, l) __builtin_amdgcn_global_load_lds( \
    (const __attribute__((address_space(1))) void*)(g), \
    (__attribute__((address_space(3))) void*)(l), 16, 0, 0)

// log2(e)/sqrt(128): folded into q at the QKV epilogue so softmax uses exp2 directly
#define QSCALE 0.12751744f

static __device__ __forceinline__ f32x4 MFMA(bf16x8 a, bf16x8 b, f32x4 c) {
    return __builtin_amdgcn_mfma_f32_16x16x32_bf16(a, b, c, 0, 0, 0);
}

// ---------------------------------------------------------------- convert f32->bf16
__global__ __launch_bounds__(256) void convert_kernel(
    const float* __restrict__ x, const float* __restrict__ wq,
    const float* __restrict__ wk, const float* __restrict__ wv,
    const float* __restrict__ wp,
    bf16* __restrict__ xb, bf16* __restrict__ wqkvb, bf16* __restrict__ wpb)
{
    int bid = blockIdx.x;
    const float* src; bf16* dst; int base;
    if (bid < 4096)      { src = x;  dst = xb;              base = bid * 2048; }
    else if (bid < 4608) { src = wq; dst = wqkvb;           base = (bid - 4096) * 2048; }
    else if (bid < 5120) { src = wk; dst = wqkvb + 1048576; base = (bid - 4608) * 2048; }
    else if (bid < 5632) { src = wv; dst = wqkvb + 2097152; base = (bid - 5120) * 2048; }
    else                 { src = wp; dst = wpb;             base = (bid - 5632) * 2048; }
    int i = base + threadIdx.x * 8;
    const f32x4* s4 = (const f32x4*)(src + i);
    f32x4 a = s4[0], c = s4[1];
    bf16x8 v;
    #pragma unroll
    for (int e = 0; e < 4; ++e) { v[e] = (bf16)a[e]; v[e + 4] = (bf16)c[e]; }
    *(bf16x8*)(dst + i) = v;
}

// ---------------------------------------------------------------- 256x128 GEMM
// v9: cut STAGED BYTES -25% at constant concurrency. All 128^2 variants stage
// 768 MB (A x24 + B x64) and land at ~8.3 TB/s aggregate => 92-100 us. BM=256
// halves B-traffic: staged = 384(A) + 192(B) = 576 MB. Geometry: 512-thread
// blocks, 8 waves (4 wr x 2 wc) of 64x64 each (per-wave reg shape == R8's
// 56-VGPR kernel), BK=32, dbuf LDS 48 KiB -> 2 blocks/CU = 16 waves/CU (2x
// R10's occupancy). Grid: QKV 32x24=768, proj 32x8=256 (R10's proven bijective
// swizzle, R14's mapping reverted). Paired-row swizzled LDS layout (R8,
// measured 0 conflicts) -- all offsets mod-8-invariant under wr in [0,4).
// Stage-first + ONE __syncthreads per iter (R7-proven).
// MODE 0: QKV epilogue (q scaled, k, v transposed per head); MODE 1: f32+bias.
template <int MODE, int NTN>
__global__ __launch_bounds__(512, 4) void gemm2(
    const bf16* __restrict__ A, const bf16* __restrict__ B,
    const float* __restrict__ bias0, const float* __restrict__ bias1,
    const float* __restrict__ bias2,
    bf16* __restrict__ q_out, bf16* __restrict__ k_out, bf16* __restrict__ vt_out,
    float* __restrict__ f_out)
{
    constexpr int K = 1024;
    constexpr int NT = K / 32;        // 32 K-tiles
    constexpr int NWG = 32 * NTN;     // 32 m-tiles of 256
    const int tid = threadIdx.x;      // 0..511
    const int lane = tid & 63;
    const int wid = tid >> 6;         // 0..7
    const int wr = wid >> 1;          // 0..3  (m quarter)
    const int wc = wid & 1;           // 0..1  (n half)
    const int l15 = lane & 15, l4 = lane >> 4;

    // bijective XCD chunk swizzle (NWG % 8 == 0)
    const int g = blockIdx.x;
    const int lin = (g & 7) * (NWG / 8) + (g >> 3);
    const int m0 = (lin / NTN) * 256, n0 = (lin % NTN) * 128;

    // [buf][A 256x32 (8192 elems) | B 128x32 (4096 elems)] = 48 KiB total
    __shared__ __align__(16) bf16 lds[2][12288];

    // staging (3 GLDS16/thread): paired-row lines; line L holds rows {2L,2L+1},
    // phys 16B slot p = tid&7 gets logical q = p ^ (L&7) -> row 2L+(q>>2),
    // kchunk q&3. (L&7) == ((tid>>3)&7) for all calls (call bases % 8 == 0).
    const int t3 = tid >> 3, pp = tid & 7;
    const int qq = pp ^ (t3 & 7);
    const int rb = 2 * t3 + (qq >> 2);    // 0..127
    const int cc = qq & 3;
    const bf16* aB = A + (size_t)(m0 + rb) * K + cc * 8;
    const bf16* bB = B + (size_t)(n0 + rb) * K + cc * 8;
    auto stage = [&](int buf, int t) {
        GLDS16(aB + t * 32,                    &lds[buf][tid * 8]);
        GLDS16(aB + (size_t)128 * K + t * 32,  &lds[buf][4096 + tid * 8]);
        GLDS16(bB + t * 32,                    &lds[buf][8192 + tid * 8]);
    };

    // frag read: row = base + f*16 + l15, kchunk = l4:
    //   line = base/2 + f*8 + (l15>>1); phys = ((l15&1)*4 + l4) ^ ((l15>>1)&7)
    const int physc = (((l15 & 1) * 4 + l4) ^ ((l15 >> 1) & 7)) * 16;
    const int aoff = (wr * 32 + (l15 >> 1)) * 128 + physc;
    const int boff = 16384 + (wc * 32 + (l15 >> 1)) * 128 + physc;
    #define RA(buf, f) (*(const bf16x8*)((const char*)lds[buf] + aoff + (f) * 1024))
    #define RB(buf, j) (*(const bf16x8*)((const char*)lds[buf] + boff + (j) * 1024))

    f32x4 acc[4][4];
    #pragma unroll
    for (int f = 0; f < 4; ++f)
        #pragma unroll
        for (int j = 0; j < 4; ++j)
            #pragma unroll
            for (int e = 0; e < 4; ++e) acc[f][j][e] = 0.f;

    stage(0, 0);
    __syncthreads();

    for (int t = 0; t < NT; ++t) {
        const int buf = t & 1;
        if (t + 1 < NT) stage(buf ^ 1, t + 1);   // issue next-tile loads FIRST
        bf16x8 af[4], bfr[4];
        #pragma unroll
        for (int f = 0; f < 4; ++f) af[f] = RA(buf, f);
        #pragma unroll
        for (int j = 0; j < 4; ++j) bfr[j] = RB(buf, j);
        __builtin_amdgcn_s_setprio(1);
        #pragma unroll
        for (int f = 0; f < 4; ++f)
            #pragma unroll
            for (int j = 0; j < 4; ++j)
                acc[f][j] = MFMA(af[f], bfr[j], acc[f][j]);
        __builtin_amdgcn_s_setprio(0);
        __syncthreads();   // drains vmcnt (stage had the whole phase to land)
    }
    #undef RA
    #undef RB

    // epilogue: C/D layout col = lane&15, row = (lane>>4)*4 + reg  [m89-verified]
    #pragma unroll
    for (int f = 0; f < 4; ++f) {
        #pragma unroll
        for (int j = 0; j < 4; ++j) {
            #pragma unroll
            for (int r = 0; r < 4; ++r) {
                int m = m0 + wr * 64 + f * 16 + l4 * 4 + r;
                int n = n0 + wc * 64 + j * 16 + l15;
                float v = acc[f][j][r];
                if (MODE == 0) {
                    if (n0 < 1024) {
                        q_out[m * 1024 + n] = (bf16)((v + bias0[n]) * QSCALE);
                    } else if (n0 < 2048) {
                        int nn = n - 1024;
                        k_out[m * 1024 + nn] = (bf16)(v + bias1[nn]);
                    } else {
                        int nn = n - 2048;
                        int hl = nn >> 7, d = nn & 127;
                        int bb = m >> 10, tt = m & 1023;
                        vt_out[((bb * 8 + hl) * 128 + d) * 1024 + tt] = (bf16)(v + bias2[nn]);
                    }
                } else {
                    f_out[m * 1024 + n] = v + bias0[n];
                }
            }
        }
    }
}

// ---------------------------------------------------------------- flash attention v4
// grid: 512 = B(8)*H(8)*(T/128); 4 waves/block, each wave owns 32 q-rows.
// QBLK=128 (bytes/MFMA 0.56 KB), un-subtracted softmax, dbuf single-barrier,
// setprio. LDS 80 KiB -> 2 blocks/CU. (unchanged from R10 -- measured good)
__global__ __launch_bounds__(256, 2) void attn_kernel(
    const bf16* __restrict__ qb, const bf16* __restrict__ kb,
    const bf16* __restrict__ vtb, const int* __restrict__ mask,
    bf16* __restrict__ yb)
{
    const int tid = threadIdx.x;
    const int lane = tid & 63;
    const int wid = tid >> 6;
    const int g = blockIdx.x;
    const int orig = (g & 7) * 64 + (g >> 3);   // bijective XCD swizzle (512 = 8*64)
    const int bh = orig >> 3;
    const int qt = orig & 7;
    const int b = bh >> 3;
    const int h = bh & 7;
    const int m0 = b * 1024 + qt * 128;
    const int l15 = lane & 15, l4 = lane >> 4;

    __shared__ __align__(16) char smem[81920];
    auto stageKV = [&](int bufKV, int kt) {
        char* Kb = smem + bufKV * 16384;
        char* Vb = smem + 32768 + bufKV * 16384;
        #pragma unroll
        for (int n = 0; n < 4; ++n)
            GLDS16(kb + (b * 1024 + kt + n * 16 + (tid >> 4)) * 1024 + h * 128 +
                       (((tid & 15) ^ ((tid >> 4) & 7)) * 8),
                   Kb + n * 4096 + tid * 16);
        #pragma unroll
        for (int n = 0; n < 4; ++n)
            GLDS16(vtb + (bh * 128 + n * 32 + (tid >> 3)) * 1024 + kt +
                       (((tid & 7) ^ ((tid >> 3) & 7)) * 8),
                   Vb + n * 4096 + tid * 16);
    };

    bf16x8 qf[2][4];
    #pragma unroll
    for (int i = 0; i < 2; ++i)
        #pragma unroll
        for (int kc = 0; kc < 4; ++kc)
            qf[i][kc] = *(const bf16x8*)(qb +
                (m0 + wid * 32 + i * 16 + l15) * 1024 + h * 128 + kc * 32 + l4 * 8);

    f32x4 o[2][8];
    #pragma unroll
    for (int i = 0; i < 2; ++i)
        #pragma unroll
        for (int jd = 0; jd < 8; ++jd)
            #pragma unroll
            for (int e = 0; e < 4; ++e) o[i][jd][e] = 0.f;
    float l_run[2][4];
    #pragma unroll
    for (int i = 0; i < 2; ++i)
        #pragma unroll
        for (int r = 0; r < 4; ++r) l_run[i][r] = 0.f;

    stageKV(0, 0);
    __syncthreads();

    for (int t = 0; t < 16; ++t) {
        const int buf = t & 1;
        const int kt = t * 64;
        if (t + 1 < 16) stageKV(buf ^ 1, kt + 64);   // issue next K/V FIRST

        int mv[4];
        #pragma unroll
        for (int j = 0; j < 4; ++j)
            mv[j] = mask[b * 1024 + kt + j * 16 + l15];

        const char* Ks = smem + buf * 16384;
        const char* Vs = smem + 32768 + buf * 16384;

        f32x4 s[2][4];
        #pragma unroll
        for (int i = 0; i < 2; ++i)
            #pragma unroll
            for (int j = 0; j < 4; ++j)
                #pragma unroll
                for (int e = 0; e < 4; ++e) s[i][j][e] = 0.f;
        #pragma unroll
        for (int kc = 0; kc < 4; ++kc) {
            bf16x8 kf[4];
            #pragma unroll
            for (int j = 0; j < 4; ++j)
                kf[j] = *(const bf16x8*)(Ks + (j * 16 + l15) * 256 +
                    (((kc * 4 + l4) ^ (lane & 7)) * 16));
            __builtin_amdgcn_s_setprio(1);
            #pragma unroll
            for (int i = 0; i < 2; ++i)
                #pragma unroll
                for (int j = 0; j < 4; ++j)
                    s[i][j] = MFMA(qf[i][kc], kf[j], s[i][j]);
            __builtin_amdgcn_s_setprio(0);
        }

        #pragma unroll
        for (int i = 0; i < 2; ++i)
            #pragma unroll
            for (int j = 0; j < 4; ++j) {
                if (mv[j] == 0) {
                    #pragma unroll
                    for (int e = 0; e < 4; ++e) s[i][j][e] = -1e30f;
                }
                #pragma unroll
                for (int r = 0; r < 4; ++r) {
                    float p = __builtin_amdgcn_exp2f(s[i][j][r]);
                    s[i][j][r] = p;
                    l_run[i][r] += p;
                }
            }

        #pragma unroll
        for (int i = 0; i < 2; ++i)
            #pragma unroll
            for (int j = 0; j < 4; ++j)
                #pragma unroll
                for (int r = 0; r < 4; ++r) {
                    int row = i * 16 + l4 * 4 + r;
                    int col = j * 16 + l15;
                    *(bf16*)(smem + 65536 + wid * 4096 + row * 128 +
                             (((col >> 3) ^ (row & 7)) * 16) + (col & 7) * 2) =
                        (bf16)s[i][j][r];
                }

        #pragma unroll
        for (int k2 = 0; k2 < 2; ++k2) {
            bf16x8 pa[2];
            #pragma unroll
            for (int i = 0; i < 2; ++i)
                pa[i] = *(const bf16x8*)(smem + 65536 + wid * 4096 +
                    (i * 16 + l15) * 128 + (((k2 * 4 + l4) ^ (l15 & 7)) * 16));
            __builtin_amdgcn_s_setprio(1);
            #pragma unroll
            for (int jd = 0; jd < 8; ++jd) {
                bf16x8 vf = *(const bf16x8*)(Vs + (jd * 16 + l15) * 128 +
                    (((k2 * 4 + l4) ^ (l15 & 7)) * 16));
                o[0][jd] = MFMA(pa[0], vf, o[0][jd]);
                o[1][jd] = MFMA(pa[1], vf, o[1][jd]);
            }
            __builtin_amdgcn_s_setprio(0);
        }
        __syncthreads();
    }

    #pragma unroll
    for (int off = 8; off >= 1; off >>= 1)
        #pragma unroll
        for (int i = 0; i < 2; ++i)
            #pragma unroll
            for (int r = 0; r < 4; ++r) l_run[i][r] += __shfl_xor(l_run[i][r], off);
    #pragma unroll
    for (int i = 0; i < 2; ++i) {
        float inv[4];
        #pragma unroll
        for (int r = 0; r < 4; ++r) inv[r] = 1.0f / fmaxf(l_run[i][r], 1e-30f);
        #pragma unroll
        for (int jd = 0; jd < 8; ++jd)
            #pragma unroll
            for (int r = 0; r < 4; ++r)
                yb[(m0 + wid * 32 + i * 16 + l4 * 4 + r) * 1024 +
                   h * 128 + jd * 16 + l15] = (bf16)(o[i][jd][r] * inv[r]);
    }
}

// ---------------------------------------------------------------- launch
extern "C" void kernel_launch(void* const* d_in, const int* in_sizes, int n_in,
                              void* d_out, int out_size, void* d_ws, size_t ws_size,
                              hipStream_t stream)
{
    (void)in_sizes; (void)n_in; (void)out_size; (void)ws_size;
    const float* x  = (const float*)d_in[0];
    const int* mask = (const int*)d_in[1];
    const float* Wq = (const float*)d_in[2];
    const float* bq = (const float*)d_in[3];
    const float* Wk = (const float*)d_in[4];
    const float* bk = (const float*)d_in[5];
    const float* Wv = (const float*)d_in[6];
    const float* bv = (const float*)d_in[7];
    const float* Wp = (const float*)d_in[8];
    const float* bp = (const float*)d_in[9];
    float* out = (float*)d_out;

    char* ws = (char*)d_ws;
    bf16* xb    = (bf16*)(ws);                      // 16 MB  x bf16 (8192 x 1024)
    bf16* wqkvb = (bf16*)(ws + (16u << 20));        //  6 MB  [Wq;Wk;Wv]
    bf16* wpb   = (bf16*)(ws + (22u << 20));        //  2 MB  Wp
    bf16* qbuf  = (bf16*)(ws + (24u << 20));        // 16 MB  q (scaled)
    bf16* kbuf  = (bf16*)(ws + (40u << 20));        // 16 MB  k
    bf16* vtb   = (bf16*)(ws + (56u << 20));        // 16 MB  v^T per (b,h)
    bf16* ybuf  = (bf16*)(ws + (72u << 20));        // 16 MB  attention out

    convert_kernel<<<6144, 256, 0, stream>>>(x, Wq, Wk, Wv, Wp, xb, wqkvb, wpb);
    gemm2<0, 24><<<768, 512, 0, stream>>>(xb, wqkvb, bq, bk, bv,
                                          qbuf, kbuf, vtb, nullptr);
    attn_kernel<<<512, 256, 0, stream>>>(qbuf, kbuf, vtb, mask, ybuf);
    gemm2<1, 8><<<256, 512, 0, stream>>>(ybuf, wpb, bp, nullptr, nullptr,
                                         nullptr, nullptr, nullptr, out);
}